// Round 6
// baseline (508.284 us; speedup 1.0000x reference)
//
#include <hip/hip_runtime.h>
#include <hip/hip_bf16.h>

// Problem: B=16,S=64 -> BS=1024 sequences, L=128 tokens, D=512, F=256 filters
// per conv width Kw in {3,4,5}, V=30000.
// out[bs, c*256 + f] = relu(max_t (conv_c(x)[t,f]) + b_c[f]), fp32.
//
// R7: persistent c-merged blocks, 16x16x32 (2m x 8n), depth-4 B ring: 442 us
//     (conv 363, Mfma 58%).
// R8: 32x32x16 at (4m x 4n) FAILED (conv 490): B 32 KB/step + gather evict.
// R9: 32x32x16 at (2m x 8n), NT gather, linear B ring: conv 410, Mfma 50%.
//     POST-MORTEM: conflicts 5.07e7 over 6.29M ds_read_b128 = 8 cyc/read.
//     32x32 A-read = 32 consecutive rows at one 16B col; row stride 512 B
//     = 0 mod 128, 3-bit (r&7) XOR spreads 32 rows over only 8 slots ->
//     4-way conflict -> ~54 B/cyc -> 607 cyc/step vs 258 MFMA. Matches
//     measured 640 cyc/step. NOT an inherent b128 cost (R7 claim wrong).
// R10: 5-bit swizzle slot = col ^ (row&31): 32 rows -> 32 distinct slots,
//     lh pair shares slot with different rows (2-way = free, m136).
//     (row+32)&31 invariant -> a1 stays +16384 off a0. (2s+lh)^e =
//     (2s)^(lh^e) -> hoist t = lh^e per tap, 2 VALU/step addressing.
//     Everything else identical to R9 for clean A/B attribution.

typedef __bf16 bf16x8 __attribute__((ext_vector_type(8)));
typedef float f32x16 __attribute__((ext_vector_type(16)));
typedef float f32x4v __attribute__((ext_vector_type(4)));

#define ROWS 132                      // 128 real + 4 zero rows (K=5 window)
#define ROWB 512                      // bytes per row per half-D buffer
#define BUF_BYTES (ROWS * ROWB)       // 67584
#define RED_OFF (2 * BUF_BYTES)       // 135168
#define LDS_TOTAL (RED_OFF + 2048)    // 137216 (red: 2 x 256 f32)

// -------- pack_w: 32x32-fragment-ordered chunks (unchanged from R8) ---------
// Chunk g = (c, k16, n32), 1024 B = 64 lanes x 16 B. Element (lane, j):
//   f = n32*32 + (lane&31), tap = k16>>5, d = (k16&31)*16 + (lane>>5)*8 + j
//   src = w_c[f][d][tap]  (layout [F][D][Kw]).  Chunk order: [c][k16][n32].
__global__ void pack_w_kernel(const float* __restrict__ w3,
                              const float* __restrict__ w4,
                              const float* __restrict__ w5,
                              __bf16* __restrict__ wq) {
    const int t    = blockIdx.x * 256 + threadIdx.x;  // 0..196607
    const int g    = t >> 6;                          // chunk 0..3071
    const int lane = t & 63;
    int rel, Kw; const float* w;
    if (g < 768)       { rel = g;        Kw = 3; w = w3; }
    else if (g < 1792) { rel = g - 768;  Kw = 4; w = w4; }
    else               { rel = g - 1792; Kw = 5; w = w5; }
    const int k16 = rel >> 3;                         // 0..Kw*32-1
    const int n32 = rel & 7;
    const int f   = n32 * 32 + (lane & 31);
    const int tap = k16 >> 5;
    const int d0  = (k16 & 31) * 16 + (lane >> 5) * 8;
    const float* src = w + ((size_t)f * 512 + d0) * Kw + tap;
    bf16x8 o;
#pragma unroll
    for (int j = 0; j < 8; ++j) o[j] = (__bf16)src[j * Kw];
    *(bf16x8*)(wq + (size_t)t * 8) = o;
}

// ---------------- persistent fused gather + conv GEMM -----------------------
// Grid 256 (1 block/CU), 4 bs/block, 1024 thr = 16 waves as 2m x 8n.
// Wave tile 64x32 = 2x1 of 32x32x16 bf16 (acc 2 x f32x16). A: two half-D
// slabs, 5-bit XOR-swizzled, resident across all 3 convs. B: one 1 KB chunk
// per step per wave, flat depth-4 register ring, linear chunk index.
__global__ __launch_bounds__(1024, 4) void conv_gemm_kernel(
        const int* __restrict__ text,
        const float* __restrict__ embed,
        const __bf16* __restrict__ wq,
        const float* __restrict__ b3,
        const float* __restrict__ b4,
        const float* __restrict__ b5,
        float* __restrict__ out) {
    extern __shared__ char lds[];
    float* const red = (float*)(lds + RED_OFF);

    const int tid  = threadIdx.x;
    const int lane = tid & 63;
    const int wave = tid >> 6;         // 0..15
    const int wm   = wave & 1;         // m-slice (64 rows)
    const int wn   = wave >> 1;        // n-slice (32 cols)
    const int l31  = lane & 31;
    const int lh   = lane >> 5;
    const int sr   = tid >> 5;         // staging row-in-pass 0..31
    const int sc   = tid & 31;         // staging col 0..31 (x16B)

    const int bsbase = blockIdx.x * 4;

    // A fragment row base + swizzled step-0 address (tap 0)
    const int arow = wm * 64 + l31;
    const int A00  = arow * 512 + ((lh ^ (arow & 31)) << 4);

    const __bf16* const bpL = wq + (size_t)wn * 512 + (size_t)lane * 8;

    // ---- gather staging: nt loads, 2 rows/thread-pass, 16 B dst/thread ----
    f32x4v G[4];
    auto issuePair = [&](int nbs, int h, int p0) {
#pragma unroll
        for (int p = 0; p < 2; ++p) {
            const int r = (p0 + p) * 32 + sr;
            const int tok = text[nbs * 128 + r];
            const f32x4v* src = (const f32x4v*)
                (embed + (size_t)tok * 512 + h * 256 + sc * 8);
            G[p * 2]     = __builtin_nontemporal_load(src);
            G[p * 2 + 1] = __builtin_nontemporal_load(src + 1);
        }
    };
    auto writePair = [&](char* bufp, int p0) {
#pragma unroll
        for (int p = 0; p < 2; ++p) {
            const int r = (p0 + p) * 32 + sr;
            const f32x4v v0 = G[p * 2], v1 = G[p * 2 + 1];
            bf16x8 o;
            o[0] = (__bf16)v0.x; o[1] = (__bf16)v0.y;
            o[2] = (__bf16)v0.z; o[3] = (__bf16)v0.w;
            o[4] = (__bf16)v1.x; o[5] = (__bf16)v1.y;
            o[6] = (__bf16)v1.z; o[7] = (__bf16)v1.w;
            *(bf16x8*)(bufp + r * ROWB + ((sc ^ (r & 31)) << 4)) = o;
        }
    };

    f32x16 acc[2];
    bf16x8 Br[4];
    bf16x8 a0, a1;

    // ---- block prolog: stage bs0 both halves, zero pad rows, fill ring ----
    issuePair(bsbase, 0, 0); writePair(lds, 0);
    issuePair(bsbase, 0, 2); writePair(lds, 2);
    issuePair(bsbase, 1, 0); writePair(lds + BUF_BYTES, 0);
    issuePair(bsbase, 1, 2); writePair(lds + BUF_BYTES, 2);
    if (tid < 128) {                   // rows 128..131, both buffers, once
        const int r = 128 + sr;
        const int off = r * ROWB + ((sc ^ (r & 31)) << 4);
        bf16x8 z = {};
        *(bf16x8*)(lds + off) = z;
        *(bf16x8*)(lds + BUF_BYTES + off) = z;
    }
#pragma unroll
    for (int k = 0; k < 4; ++k)        // ring: c0 chunks (k16) 0..3
        Br[k] = *(const bf16x8*)(bpL + (size_t)k * 4096);
    __syncthreads();

#pragma unroll 1
    for (int i = 0; i < 4; ++i) {
        const int bs  = bsbase + i;
        const int nbs = bs + 1;
        const bool stg = (i < 3);
#pragma unroll 1
        for (int c = 0; c < 3; ++c) {
            const int KW = 3 + c;
            const size_t cb  = (c == 0) ? 0 : (c == 1) ? 393216 : 917504;
            const size_t cbn = (c == 0) ? 393216 : (c == 1) ? 917504 : 0;
            const __bf16* bpc = bpL + cb;
            const __bf16* bpn = bpL + cbn;
            const bool lastc = stg && (c == 2);

#pragma unroll
            for (int r = 0; r < 16; ++r) { acc[0][r] = 0.f; acc[1][r] = 0.f; }

            if (lastc) issuePair(nbs, 0, 0);   // hide gather under c2 K loop

            // cold A for step 0 (slab may have been restaged)
            a0 = *(const bf16x8*)(lds + A00);
            a1 = *(const bf16x8*)(lds + A00 + 16384);

#pragma unroll 1
            for (int tap = 0; tap < KW; ++tap) {
                const int row = arow + tap;
                const int tx  = lh ^ (row & 31);       // (2s+lh)^e = (2s)^tx
                const int rb  = row * 512;
                const int c0o = tx << 4;               // s=0 col offset
                const int r2  = row + 1;
                const int NT0 = r2 * 512 + ((lh ^ (r2 & 31)) << 4);
#pragma unroll
                for (int dh = 0; dh < 2; ++dh) {
                    const int bo = dh ? BUF_BYTES : 0;
                    const int s0 = tap * 32 + dh * 16;
                    // B refill bases: chunk index s0+4+d (d<12), else next
                    // segment / next stream (tail) chunks 0..3.
                    const __bf16* q0 = bpc + (size_t)(s0 + 4) * 4096;
                    const __bf16* q1 = (dh == 1 && tap == KW - 1)
                                           ? bpn : (q0 + 12 * 4096);
#pragma unroll
                    for (int d = 0; d < 16; ++d) {
                        int na;
                        if (d < 15)
                            na = bo + rb + (((2 * (d + 1)) ^ tx) << 4);
                        else if (dh == 0)
                            na = BUF_BYTES + rb + c0o; // same tap, half 1
                        else
                            na = NT0;                  // next tap (or dummy)
                        const bf16x8 n0 = *(const bf16x8*)(lds + na);
                        const bf16x8 n1 = *(const bf16x8*)(lds + na + 16384);
                        __builtin_amdgcn_s_setprio(1);
                        acc[0] = __builtin_amdgcn_mfma_f32_32x32x16_bf16(
                            a0, Br[d & 3], acc[0], 0, 0, 0);
                        acc[1] = __builtin_amdgcn_mfma_f32_32x32x16_bf16(
                            a1, Br[d & 3], acc[1], 0, 0, 0);
                        __builtin_amdgcn_s_setprio(0);
                        Br[d & 3] = (d < 12)
                            ? *(const bf16x8*)(q0 + (size_t)d * 4096)
                            : *(const bf16x8*)(q1 + (size_t)(d - 12) * 4096);
                        a0 = n0; a1 = n1;
                    }
                }
            }

            // ---- epilogue: masked max over t, cross-lane, cross-wave ----
            const int Tv = 126 - c;                // 126/125/124 valid
            float cmax = -3.0e38f;
#pragma unroll
            for (int mt = 0; mt < 2; ++mt)
#pragma unroll
                for (int r = 0; r < 16; ++r) {
                    const int t = wm * 64 + mt * 32
                                + (r & 3) + 8 * (r >> 2) + 4 * lh;
                    if (t < Tv) cmax = fmaxf(cmax, acc[mt][r]);
                }
            cmax = fmaxf(cmax, __shfl_xor(cmax, 32, 64));

            __syncthreads();   // all slab reads + prev red consumers done
            if (lane < 32) red[wm * 256 + wn * 32 + l31] = cmax;
            if (lastc) {       // restage bs+1 (p0 already in flight)
                writePair(lds, 0);
                issuePair(nbs, 0, 2); writePair(lds, 2);
                issuePair(nbs, 1, 0); writePair(lds + BUF_BYTES, 0);
                issuePair(nbs, 1, 2); writePair(lds + BUF_BYTES, 2);
            }
            __syncthreads();   // red + restage writes visible
            if (tid < 256) {
                const float* bias = (c == 0) ? b3 : (c == 1) ? b4 : b5;
                const float vv = fmaxf(red[tid], red[256 + tid]) + bias[tid];
                __builtin_nontemporal_store(fmaxf(vv, 0.f),
                    &out[(size_t)bs * 768 + c * 256 + tid]);
            }
        }
    }
}

extern "C" void kernel_launch(void* const* d_in, const int* in_sizes, int n_in,
                              void* d_out, int out_size, void* d_ws, size_t ws_size,
                              hipStream_t stream) {
    const int*   text  = (const int*)d_in[0];
    const float* embed = (const float*)d_in[1];
    const float* w3    = (const float*)d_in[2];
    const float* b3    = (const float*)d_in[3];
    const float* w4    = (const float*)d_in[4];
    const float* b4    = (const float*)d_in[5];
    const float* w5    = (const float*)d_in[6];
    const float* b5    = (const float*)d_in[7];
    float* out = (float*)d_out;

    __bf16* wq = (__bf16*)d_ws;                 // 1572864 bf16 = 3.1 MB

    (void)hipFuncSetAttribute((const void*)conv_gemm_kernel,
                              hipFuncAttributeMaxDynamicSharedMemorySize,
                              LDS_TOTAL);

    pack_w_kernel<<<768, 256, 0, stream>>>(w3, w4, w5, wq);
    conv_gemm_kernel<<<256, 1024, LDS_TOTAL, stream>>>(text, embed, wq,
                                                       b3, b4, b5, out);
}

// Round 7
// 493.918 us; speedup vs baseline: 1.0291x; 1.0291x over previous
//
#include <hip/hip_runtime.h>
#include <hip/hip_bf16.h>

// Problem: B=16,S=64 -> BS=1024 sequences, L=128 tokens, D=512, F=256 filters
// per conv width Kw in {3,4,5}, V=30000.
// out[bs, c*256 + f] = relu(max_t (conv_c(x)[t,f]) + b_c[f]), fp32.
//
// R7: 16x16x32 (2m x 8n), depth-4 B ring: conv 363, Mfma 58%.
// R8: 32x32x16 at (4m x 4n) FAILED (conv 490): B 32 KB/step + gather evict.
// R9: 32x32x16 at (2m x 8n): conv 410, Mfma 50% — 4-way A-read conflicts.
// R10: 5-bit swizzle col^(row&31): conflicts 5.07e7 -> 0, time UNCHANGED
//     (417, Mfma 50%). Step = 651 cyc ~= LDS 384 + MFMA 258: 1-step A
//     lookahead serializes LDS queue latency with compute.
// R11: depth-4 A ring (2-step lookahead), mirroring the B ring. Slot s&3
//     computed, slot (s+2)&3 loaded each step; tap/dh boundaries precomputed
//     (rb2/tx2), last-tap loads dummies (each conv cold-loads slots 0,1).
//     Everything else identical to R10.

typedef __bf16 bf16x8 __attribute__((ext_vector_type(8)));
typedef float f32x16 __attribute__((ext_vector_type(16)));
typedef float f32x4v __attribute__((ext_vector_type(4)));

#define ROWS 132                      // 128 real + 4 zero rows (K=5 window)
#define ROWB 512                      // bytes per row per half-D buffer
#define BUF_BYTES (ROWS * ROWB)       // 67584
#define RED_OFF (2 * BUF_BYTES)       // 135168
#define LDS_TOTAL (RED_OFF + 2048)    // 137216 (red: 2 x 256 f32)

// -------- pack_w: 32x32-fragment-ordered chunks (unchanged from R8) ---------
// Chunk g = (c, k16, n32), 1024 B = 64 lanes x 16 B. Element (lane, j):
//   f = n32*32 + (lane&31), tap = k16>>5, d = (k16&31)*16 + (lane>>5)*8 + j
//   src = w_c[f][d][tap]  (layout [F][D][Kw]).  Chunk order: [c][k16][n32].
__global__ void pack_w_kernel(const float* __restrict__ w3,
                              const float* __restrict__ w4,
                              const float* __restrict__ w5,
                              __bf16* __restrict__ wq) {
    const int t    = blockIdx.x * 256 + threadIdx.x;  // 0..196607
    const int g    = t >> 6;                          // chunk 0..3071
    const int lane = t & 63;
    int rel, Kw; const float* w;
    if (g < 768)       { rel = g;        Kw = 3; w = w3; }
    else if (g < 1792) { rel = g - 768;  Kw = 4; w = w4; }
    else               { rel = g - 1792; Kw = 5; w = w5; }
    const int k16 = rel >> 3;                         // 0..Kw*32-1
    const int n32 = rel & 7;
    const int f   = n32 * 32 + (lane & 31);
    const int tap = k16 >> 5;
    const int d0  = (k16 & 31) * 16 + (lane >> 5) * 8;
    const float* src = w + ((size_t)f * 512 + d0) * Kw + tap;
    bf16x8 o;
#pragma unroll
    for (int j = 0; j < 8; ++j) o[j] = (__bf16)src[j * Kw];
    *(bf16x8*)(wq + (size_t)t * 8) = o;
}

// ---------------- persistent fused gather + conv GEMM -----------------------
// Grid 256 (1 block/CU), 4 bs/block, 1024 thr = 16 waves as 2m x 8n.
// Wave tile 64x32 = 2x1 of 32x32x16 bf16 (acc 2 x f32x16). A: two half-D
// slabs, 5-bit XOR-swizzled, resident across all 3 convs; depth-4 A ring
// (2-step lookahead). B: 1 KB chunk per step per wave, depth-4 ring.
__global__ __launch_bounds__(1024, 4) void conv_gemm_kernel(
        const int* __restrict__ text,
        const float* __restrict__ embed,
        const __bf16* __restrict__ wq,
        const float* __restrict__ b3,
        const float* __restrict__ b4,
        const float* __restrict__ b5,
        float* __restrict__ out) {
    extern __shared__ char lds[];
    float* const red = (float*)(lds + RED_OFF);

    const int tid  = threadIdx.x;
    const int lane = tid & 63;
    const int wave = tid >> 6;         // 0..15
    const int wm   = wave & 1;         // m-slice (64 rows)
    const int wn   = wave >> 1;        // n-slice (32 cols)
    const int l31  = lane & 31;
    const int lh   = lane >> 5;
    const int sr   = tid >> 5;         // staging row-in-pass 0..31
    const int sc   = tid & 31;         // staging col 0..31 (x16B)

    const int bsbase = blockIdx.x * 4;

    // A fragment row base (tap 0)
    const int arow = wm * 64 + l31;
    const int tx0  = lh ^ (arow & 31);
    const int A00  = arow * 512;

    const __bf16* const bpL = wq + (size_t)wn * 512 + (size_t)lane * 8;

    // ---- gather staging: nt loads, 2 rows/thread-pass, 16 B dst/thread ----
    f32x4v G[4];
    auto issuePair = [&](int nbs, int h, int p0) {
#pragma unroll
        for (int p = 0; p < 2; ++p) {
            const int r = (p0 + p) * 32 + sr;
            const int tok = text[nbs * 128 + r];
            const f32x4v* src = (const f32x4v*)
                (embed + (size_t)tok * 512 + h * 256 + sc * 8);
            G[p * 2]     = __builtin_nontemporal_load(src);
            G[p * 2 + 1] = __builtin_nontemporal_load(src + 1);
        }
    };
    auto writePair = [&](char* bufp, int p0) {
#pragma unroll
        for (int p = 0; p < 2; ++p) {
            const int r = (p0 + p) * 32 + sr;
            const f32x4v v0 = G[p * 2], v1 = G[p * 2 + 1];
            bf16x8 o;
            o[0] = (__bf16)v0.x; o[1] = (__bf16)v0.y;
            o[2] = (__bf16)v0.z; o[3] = (__bf16)v0.w;
            o[4] = (__bf16)v1.x; o[5] = (__bf16)v1.y;
            o[6] = (__bf16)v1.z; o[7] = (__bf16)v1.w;
            *(bf16x8*)(bufp + r * ROWB + ((sc ^ (r & 31)) << 4)) = o;
        }
    };

    f32x16 acc[2];
    bf16x8 Br[4];
    bf16x8 A[4][2];                    // depth-4 A ring (2-step lookahead)

    // ---- block prolog: stage bs0 both halves, zero pad rows, fill ring ----
    issuePair(bsbase, 0, 0); writePair(lds, 0);
    issuePair(bsbase, 0, 2); writePair(lds, 2);
    issuePair(bsbase, 1, 0); writePair(lds + BUF_BYTES, 0);
    issuePair(bsbase, 1, 2); writePair(lds + BUF_BYTES, 2);
    if (tid < 128) {                   // rows 128..131, both buffers, once
        const int r = 128 + sr;
        const int off = r * ROWB + ((sc ^ (r & 31)) << 4);
        bf16x8 z = {};
        *(bf16x8*)(lds + off) = z;
        *(bf16x8*)(lds + BUF_BYTES + off) = z;
    }
#pragma unroll
    for (int k = 0; k < 4; ++k)        // ring: c0 chunks (k16) 0..3
        Br[k] = *(const bf16x8*)(bpL + (size_t)k * 4096);
    __syncthreads();

#pragma unroll 1
    for (int i = 0; i < 4; ++i) {
        const int bs  = bsbase + i;
        const int nbs = bs + 1;
        const bool stg = (i < 3);
#pragma unroll 1
        for (int c = 0; c < 3; ++c) {
            const int KW = 3 + c;
            const size_t cb  = (c == 0) ? 0 : (c == 1) ? 393216 : 917504;
            const size_t cbn = (c == 0) ? 393216 : (c == 1) ? 917504 : 0;
            const __bf16* bpc = bpL + cb;
            const __bf16* bpn = bpL + cbn;
            const bool lastc = stg && (c == 2);

#pragma unroll
            for (int r = 0; r < 16; ++r) { acc[0][r] = 0.f; acc[1][r] = 0.f; }

            if (lastc) issuePair(nbs, 0, 0);   // hide gather under c2 K loop

            // cold A: steps 0,1 of tap 0 (buf0) into slots 0,1
            A[0][0] = *(const bf16x8*)(lds + A00 + (tx0 << 4));
            A[0][1] = *(const bf16x8*)(lds + A00 + (tx0 << 4) + 16384);
            A[1][0] = *(const bf16x8*)(lds + A00 + ((2 ^ tx0) << 4));
            A[1][1] = *(const bf16x8*)(lds + A00 + ((2 ^ tx0) << 4) + 16384);

#pragma unroll 1
            for (int tap = 0; tap < KW; ++tap) {
                const int row = arow + tap;
                const int tx  = lh ^ (row & 31);       // (2s+lh)^e = (2s)^tx
                const int rb  = row * 512;
                const bool last = (tap == KW - 1);
                const int r2  = row + 1;               // next-tap row (buf0)
                const int tx2 = lh ^ (r2 & 31);
                const int rb2 = r2 * 512;
#pragma unroll
                for (int dh = 0; dh < 2; ++dh) {
                    const int bo = dh ? BUF_BYTES : 0;
                    const int s0 = tap * 32 + dh * 16;
                    // B refill bases: chunk index s0+4+d (d<12), else next
                    // segment / next stream (tail) chunks 0..3.
                    const __bf16* q0 = bpc + (size_t)(s0 + 4) * 4096;
                    const __bf16* q1 = (dh == 1 && tap == KW - 1)
                                           ? bpn : (q0 + 12 * 4096);
#pragma unroll
                    for (int d = 0; d < 16; ++d) {
                        const int s = dh * 16 + d;     // flat step in tap
                        const int u = s + 2;           // A-load target step
                        int na;
                        if (u < 16)
                            na = rb + (((2 * u) ^ tx) << 4);
                        else if (u < 32)
                            na = BUF_BYTES + rb + (((2 * (u - 16)) ^ tx) << 4);
                        else if (!last)
                            na = rb2 + (((2 * (u - 32)) ^ tx2) << 4);
                        else
                            na = rb + (tx << 4);       // dummy (cold reload)
                        const int cs = s & 3, ps = u & 3;
                        __builtin_amdgcn_s_setprio(1);
                        acc[0] = __builtin_amdgcn_mfma_f32_32x32x16_bf16(
                            A[cs][0], Br[cs], acc[0], 0, 0, 0);
                        acc[1] = __builtin_amdgcn_mfma_f32_32x32x16_bf16(
                            A[cs][1], Br[cs], acc[1], 0, 0, 0);
                        __builtin_amdgcn_s_setprio(0);
                        A[ps][0] = *(const bf16x8*)(lds + na);
                        A[ps][1] = *(const bf16x8*)(lds + na + 16384);
                        Br[cs] = (d < 12)
                            ? *(const bf16x8*)(q0 + (size_t)d * 4096)
                            : *(const bf16x8*)(q1 + (size_t)(d - 12) * 4096);
                    }
                }
            }

            // ---- epilogue: masked max over t, cross-lane, cross-wave ----
            const int Tv = 126 - c;                // 126/125/124 valid
            float cmax = -3.0e38f;
#pragma unroll
            for (int mt = 0; mt < 2; ++mt)
#pragma unroll
                for (int r = 0; r < 16; ++r) {
                    const int t = wm * 64 + mt * 32
                                + (r & 3) + 8 * (r >> 2) + 4 * lh;
                    if (t < Tv) cmax = fmaxf(cmax, acc[mt][r]);
                }
            cmax = fmaxf(cmax, __shfl_xor(cmax, 32, 64));

            __syncthreads();   // all slab reads + prev red consumers done
            if (lane < 32) red[wm * 256 + wn * 32 + l31] = cmax;
            if (lastc) {       // restage bs+1 (p0 already in flight)
                writePair(lds, 0);
                issuePair(nbs, 0, 2); writePair(lds, 2);
                issuePair(nbs, 1, 0); writePair(lds + BUF_BYTES, 0);
                issuePair(nbs, 1, 2); writePair(lds + BUF_BYTES, 2);
            }
            __syncthreads();   // red + restage writes visible
            if (tid < 256) {
                const float* bias = (c == 0) ? b3 : (c == 1) ? b4 : b5;
                const float vv = fmaxf(red[tid], red[256 + tid]) + bias[tid];
                __builtin_nontemporal_store(fmaxf(vv, 0.f),
                    &out[(size_t)bs * 768 + c * 256 + tid]);
            }
        }
    }
}

extern "C" void kernel_launch(void* const* d_in, const int* in_sizes, int n_in,
                              void* d_out, int out_size, void* d_ws, size_t ws_size,
                              hipStream_t stream) {
    const int*   text  = (const int*)d_in[0];
    const float* embed = (const float*)d_in[1];
    const float* w3    = (const float*)d_in[2];
    const float* b3    = (const float*)d_in[3];
    const float* w4    = (const float*)d_in[4];
    const float* b4    = (const float*)d_in[5];
    const float* w5    = (const float*)d_in[6];
    const float* b5    = (const float*)d_in[7];
    float* out = (float*)d_out;

    __bf16* wq = (__bf16*)d_ws;                 // 1572864 bf16 = 3.1 MB

    (void)hipFuncSetAttribute((const void*)conv_gemm_kernel,
                              hipFuncAttributeMaxDynamicSharedMemorySize,
                              LDS_TOTAL);

    pack_w_kernel<<<768, 256, 0, stream>>>(w3, w4, w5, wq);
    conv_gemm_kernel<<<256, 1024, LDS_TOTAL, stream>>>(text, embed, wq,
                                                       b3, b4, b5, out);
}

// Round 8
// 458.597 us; speedup vs baseline: 1.1083x; 1.0770x over previous
//
#include <hip/hip_runtime.h>
#include <hip/hip_bf16.h>

// Problem: B=16,S=64 -> BS=1024 sequences, L=128 tokens, D=512, F=256 filters
// per conv width Kw in {3,4,5}, V=30000.
// out[bs, c*256 + f] = relu(max_t (conv_c(x)[t,f]) + b_c[f]), fp32.
//
// R7:  16x16x32 (2m x 8n): conv 363, Mfma 58%.
// R9:  32x32x16 (2m x 8n): conv 410 — 4-way A-read conflicts.
// R10: 5-bit swizzle: conflicts -> 0, time unchanged (417). Step 633 cyc
//      = LDS 384 + MFMA 258 serialized.
// R11: depth-4 A ring: 405. Deeper lookahead does NOT break the serial-
//      ization -> attack the LDS BYTES instead.
// R12: 8 waves (2m x 4n), wave tile 64x64, 4 MFMA/step/wave: per k16-step
//      A-LDS 32->16 KB (192 cyc), B-L2 16 KB unchanged, MFMA 258 unchanged.
//      This is the unique decomposition with A<=16K AND B<=16K (R8 showed
//      B=32K overruns L2). 2 waves/SIMD, but VGPR cap 256 -> depth-4 A+B
//      rings and G[8] gather batches keep every load >=2 steps ahead.
//      All R11 addressing (swizzle, +16384 m-frag, flat B ring) unchanged.

typedef __bf16 bf16x8 __attribute__((ext_vector_type(8)));
typedef float f32x16 __attribute__((ext_vector_type(16)));
typedef float f32x4v __attribute__((ext_vector_type(4)));

#define ROWS 132                      // 128 real + 4 zero rows (K=5 window)
#define ROWB 512                      // bytes per row per half-D buffer
#define BUF_BYTES (ROWS * ROWB)       // 67584
#define RED_OFF (2 * BUF_BYTES)       // 135168
#define LDS_TOTAL (RED_OFF + 2048)    // 137216 (red: 2 x 256 f32)

// -------- pack_w: 32x32-fragment-ordered chunks (unchanged from R8) ---------
// Chunk g = (c, k16, n32), 1024 B = 64 lanes x 16 B. Element (lane, j):
//   f = n32*32 + (lane&31), tap = k16>>5, d = (k16&31)*16 + (lane>>5)*8 + j
//   src = w_c[f][d][tap]  (layout [F][D][Kw]).  Chunk order: [c][k16][n32].
__global__ void pack_w_kernel(const float* __restrict__ w3,
                              const float* __restrict__ w4,
                              const float* __restrict__ w5,
                              __bf16* __restrict__ wq) {
    const int t    = blockIdx.x * 256 + threadIdx.x;  // 0..196607
    const int g    = t >> 6;                          // chunk 0..3071
    const int lane = t & 63;
    int rel, Kw; const float* w;
    if (g < 768)       { rel = g;        Kw = 3; w = w3; }
    else if (g < 1792) { rel = g - 768;  Kw = 4; w = w4; }
    else               { rel = g - 1792; Kw = 5; w = w5; }
    const int k16 = rel >> 3;                         // 0..Kw*32-1
    const int n32 = rel & 7;
    const int f   = n32 * 32 + (lane & 31);
    const int tap = k16 >> 5;
    const int d0  = (k16 & 31) * 16 + (lane >> 5) * 8;
    const float* src = w + ((size_t)f * 512 + d0) * Kw + tap;
    bf16x8 o;
#pragma unroll
    for (int j = 0; j < 8; ++j) o[j] = (__bf16)src[j * Kw];
    *(bf16x8*)(wq + (size_t)t * 8) = o;
}

// ---------------- persistent fused gather + conv GEMM -----------------------
// Grid 256 (1 block/CU), 4 bs/block, 512 thr = 8 waves as 2m x 4n.
// Wave tile 64x64 = 2x2 of 32x32x16 bf16 (acc 2x2 f32x16). A: two half-D
// slabs, 5-bit XOR-swizzled, resident across all 3 convs; depth-4 A ring.
// B: 2 chunks (2 KB) per step per wave, depth-4 ring, flat chunk index.
__global__ __launch_bounds__(512, 2) void conv_gemm_kernel(
        const int* __restrict__ text,
        const float* __restrict__ embed,
        const __bf16* __restrict__ wq,
        const float* __restrict__ b3,
        const float* __restrict__ b4,
        const float* __restrict__ b5,
        float* __restrict__ out) {
    extern __shared__ char lds[];
    float* const red = (float*)(lds + RED_OFF);

    const int tid  = threadIdx.x;
    const int lane = tid & 63;
    const int wave = tid >> 6;         // 0..7
    const int wm   = wave & 1;         // m-slice (64 rows)
    const int wn   = wave >> 1;        // n-slice (64 cols)
    const int l31  = lane & 31;
    const int lh   = lane >> 5;
    const int sr   = tid >> 5;         // staging row-in-pass 0..15
    const int sc   = tid & 31;         // staging col 0..31 (x16B)

    const int bsbase = blockIdx.x * 4;

    // A fragment row base (tap 0); second m-frag is +32 rows = +16384 B
    const int arow = wm * 64 + l31;
    const int tx0  = lh ^ (arow & 31);
    const int A00  = arow * 512;

    // B: wave covers n32 = wn*2, wn*2+1 (two consecutive chunks)
    const __bf16* const bpL = wq + (size_t)wn * 1024 + (size_t)lane * 8;

    // ---- gather staging: 4 passes x 16 rows per quad, 16 B dst/thread ----
    f32x4v G[8];
    auto issueQuad = [&](int nbs, int h, int p0) {
#pragma unroll
        for (int p = 0; p < 4; ++p) {
            const int r = (p0 + p) * 16 + sr;
            const int tok = text[nbs * 128 + r];
            const f32x4v* src = (const f32x4v*)
                (embed + (size_t)tok * 512 + h * 256 + sc * 8);
            G[p * 2]     = __builtin_nontemporal_load(src);
            G[p * 2 + 1] = __builtin_nontemporal_load(src + 1);
        }
    };
    auto writeQuad = [&](char* bufp, int p0) {
#pragma unroll
        for (int p = 0; p < 4; ++p) {
            const int r = (p0 + p) * 16 + sr;
            const f32x4v v0 = G[p * 2], v1 = G[p * 2 + 1];
            bf16x8 o;
            o[0] = (__bf16)v0.x; o[1] = (__bf16)v0.y;
            o[2] = (__bf16)v0.z; o[3] = (__bf16)v0.w;
            o[4] = (__bf16)v1.x; o[5] = (__bf16)v1.y;
            o[6] = (__bf16)v1.z; o[7] = (__bf16)v1.w;
            *(bf16x8*)(bufp + r * ROWB + ((sc ^ (r & 31)) << 4)) = o;
        }
    };

    f32x16 acc[2][2];
    bf16x8 Br[4][2];                   // depth-4 B ring x 2 n-frags
    bf16x8 A[4][2];                    // depth-4 A ring x 2 m-frags

    auto loadB = [&](int slot, const __bf16* p) {
        Br[slot][0] = *(const bf16x8*)(p);
        Br[slot][1] = *(const bf16x8*)(p + 512);
    };

    // ---- block prolog: stage bs0 both halves, zero pad rows, fill ring ----
    issueQuad(bsbase, 0, 0); writeQuad(lds, 0);
    issueQuad(bsbase, 0, 4); writeQuad(lds, 4);
    issueQuad(bsbase, 1, 0); writeQuad(lds + BUF_BYTES, 0);
    issueQuad(bsbase, 1, 4); writeQuad(lds + BUF_BYTES, 4);
    if (tid < 128) {                   // rows 128..131, both buffers, once
        const int r = 128 + (tid >> 5);
        const int off = r * ROWB + ((sc ^ (r & 31)) << 4);
        bf16x8 z = {};
        *(bf16x8*)(lds + off) = z;
        *(bf16x8*)(lds + BUF_BYTES + off) = z;
    }
#pragma unroll
    for (int k = 0; k < 4; ++k)        // ring: c0 steps (k16) 0..3
        loadB(k, bpL + (size_t)k * 4096);
    __syncthreads();

#pragma unroll 1
    for (int i = 0; i < 4; ++i) {
        const int bs  = bsbase + i;
        const int nbs = bs + 1;
        const bool stg = (i < 3);
#pragma unroll 1
        for (int c = 0; c < 3; ++c) {
            const int KW = 3 + c;
            const size_t cb  = (c == 0) ? 0 : (c == 1) ? 393216 : 917504;
            const size_t cbn = (c == 0) ? 393216 : (c == 1) ? 917504 : 0;
            const __bf16* bpc = bpL + cb;
            const __bf16* bpn = bpL + cbn;
            const bool lastc = stg && (c == 2);

#pragma unroll
            for (int mt = 0; mt < 2; ++mt)
#pragma unroll
                for (int nt = 0; nt < 2; ++nt)
#pragma unroll
                    for (int r = 0; r < 16; ++r) acc[mt][nt][r] = 0.f;

            if (lastc) issueQuad(nbs, 0, 0);   // hide under c2 K loop

            // cold A: steps 0,1 of tap 0 (buf0) into slots 0,1
            A[0][0] = *(const bf16x8*)(lds + A00 + (tx0 << 4));
            A[0][1] = *(const bf16x8*)(lds + A00 + (tx0 << 4) + 16384);
            A[1][0] = *(const bf16x8*)(lds + A00 + ((2 ^ tx0) << 4));
            A[1][1] = *(const bf16x8*)(lds + A00 + ((2 ^ tx0) << 4) + 16384);

#pragma unroll 1
            for (int tap = 0; tap < KW; ++tap) {
                const int row = arow + tap;
                const int tx  = lh ^ (row & 31);       // (2s+lh)^e = (2s)^tx
                const int rb  = row * 512;
                const bool last = (tap == KW - 1);
                const int r2  = row + 1;               // next-tap row (buf0)
                const int tx2 = lh ^ (r2 & 31);
                const int rb2 = r2 * 512;
#pragma unroll
                for (int dh = 0; dh < 2; ++dh) {
                    const int s0 = tap * 32 + dh * 16;
                    // B refill: chunk-pair index s0+4+j (j<12), else across
                    // the dh/tap boundary / next stream (chunks contiguous).
                    const __bf16* q0 = bpc + (size_t)(s0 + 4) * 4096;
                    const __bf16* q1 = (dh == 1 && last)
                                           ? bpn : (q0 + 12 * 4096);
#pragma unroll
                    for (int j = 0; j < 16; ++j) {
                        const int s = dh * 16 + j;     // flat step in tap
                        const int u = s + 2;           // A-load target step
                        int na;
                        if (u < 16)
                            na = rb + (((2 * u) ^ tx) << 4);
                        else if (u < 32)
                            na = BUF_BYTES + rb + (((2 * (u - 16)) ^ tx) << 4);
                        else if (!last)
                            na = rb2 + (((2 * (u - 32)) ^ tx2) << 4);
                        else
                            na = rb + (tx << 4);       // dummy (cold reload)
                        const int cs = s & 3, ps = u & 3;
                        __builtin_amdgcn_s_setprio(1);
                        acc[0][0] = __builtin_amdgcn_mfma_f32_32x32x16_bf16(
                            A[cs][0], Br[cs][0], acc[0][0], 0, 0, 0);
                        acc[0][1] = __builtin_amdgcn_mfma_f32_32x32x16_bf16(
                            A[cs][0], Br[cs][1], acc[0][1], 0, 0, 0);
                        acc[1][0] = __builtin_amdgcn_mfma_f32_32x32x16_bf16(
                            A[cs][1], Br[cs][0], acc[1][0], 0, 0, 0);
                        acc[1][1] = __builtin_amdgcn_mfma_f32_32x32x16_bf16(
                            A[cs][1], Br[cs][1], acc[1][1], 0, 0, 0);
                        __builtin_amdgcn_s_setprio(0);
                        A[ps][0] = *(const bf16x8*)(lds + na);
                        A[ps][1] = *(const bf16x8*)(lds + na + 16384);
                        loadB(cs, (j < 12) ? (q0 + (size_t)j * 4096)
                                           : (q1 + (size_t)(j - 12) * 4096));
                    }
                }
            }

            // ---- epilogue: masked max over t, cross-lane, cross-wave ----
            const int Tv = 126 - c;                // 126/125/124 valid
            float cmax[2];
#pragma unroll
            for (int nt = 0; nt < 2; ++nt) {
                float mx = -3.0e38f;
#pragma unroll
                for (int mt = 0; mt < 2; ++mt)
#pragma unroll
                    for (int r = 0; r < 16; ++r) {
                        const int t = wm * 64 + mt * 32
                                    + (r & 3) + 8 * (r >> 2) + 4 * lh;
                        if (t < Tv) mx = fmaxf(mx, acc[mt][nt][r]);
                    }
                mx = fmaxf(mx, __shfl_xor(mx, 32, 64));
                cmax[nt] = mx;
            }

            __syncthreads();   // all slab reads + prev red consumers done
            if (lane < 32) {
#pragma unroll
                for (int nt = 0; nt < 2; ++nt)
                    red[wm * 256 + wn * 64 + nt * 32 + l31] = cmax[nt];
            }
            if (lastc) {       // restage bs+1 (h0 rows 0..63 already in G)
                writeQuad(lds, 0);
                issueQuad(nbs, 0, 4); writeQuad(lds, 4);
                issueQuad(nbs, 1, 0); writeQuad(lds + BUF_BYTES, 0);
                issueQuad(nbs, 1, 4); writeQuad(lds + BUF_BYTES, 4);
            }
            __syncthreads();   // red + restage writes visible
            if (tid < 256) {
                const float* bias = (c == 0) ? b3 : (c == 1) ? b4 : b5;
                const float vv = fmaxf(red[tid], red[256 + tid]) + bias[tid];
                __builtin_nontemporal_store(fmaxf(vv, 0.f),
                    &out[(size_t)bs * 768 + c * 256 + tid]);
            }
        }
    }
}

extern "C" void kernel_launch(void* const* d_in, const int* in_sizes, int n_in,
                              void* d_out, int out_size, void* d_ws, size_t ws_size,
                              hipStream_t stream) {
    const int*   text  = (const int*)d_in[0];
    const float* embed = (const float*)d_in[1];
    const float* w3    = (const float*)d_in[2];
    const float* b3    = (const float*)d_in[3];
    const float* w4    = (const float*)d_in[4];
    const float* b4    = (const float*)d_in[5];
    const float* w5    = (const float*)d_in[6];
    const float* b5    = (const float*)d_in[7];
    float* out = (float*)d_out;

    __bf16* wq = (__bf16*)d_ws;                 // 1572864 bf16 = 3.1 MB

    (void)hipFuncSetAttribute((const void*)conv_gemm_kernel,
                              hipFuncAttributeMaxDynamicSharedMemorySize,
                              LDS_TOTAL);

    pack_w_kernel<<<768, 256, 0, stream>>>(w3, w4, w5, wq);
    conv_gemm_kernel<<<256, 512, LDS_TOTAL, stream>>>(text, embed, wq,
                                                      b3, b4, b5, out);
}

// Round 9
// 442.271 us; speedup vs baseline: 1.1493x; 1.0369x over previous
//
#include <hip/hip_runtime.h>
#include <hip/hip_bf16.h>

// Problem: B=16,S=64 -> BS=1024 sequences, L=128 tokens, D=512, F=256 filters
// per conv width Kw in {3,4,5}, V=30000.
// out[bs, c*256 + f] = relu(max_t (conv_c(x)[t,f]) + b_c[f]), fp32.
//
// R7:  16x16x32, 16 waves (2m x 8n, 4/SIMD): conv 363 = 1135 TF. BEST.
// R8-R12: 32x32x16 family (conflict fix, A/B rings, 8-wave): all 390-417.
//      Higher per-MFMA efficiency lost to 2-wave/SIMD latency hiding.
//      Verdict: revert to R7, fix its one diagnosed defect.
// R13: R7 verbatim + (a) corrected swizzle: R7's granule^=(r&7) collided
//      row bits with lk bits -> 4-way conflicts (5.03e7 cyc, ~256 cyc/step
//      tax). New: byte ^= ((row&7)<<6) — row-XOR above lk bits; granule =
//      lk | ((q^(row&7))<<2) -> uniform 2-way over 32 banks = free.
//      Read addr: base[mt] + ((q<<6)^e), e = ((lm+tap)&7)<<6 (mt-invariant,
//      (A^B)+C valid since lk*16 < 64). (b) non-temporal embed gather.

typedef __bf16 bf16x8 __attribute__((ext_vector_type(8)));
typedef float f32x4 __attribute__((ext_vector_type(4)));

#define ROWS 132                      // 128 real + 4 zero rows (K=5 window)
#define ROWB 512                      // bytes per row per half-D buffer
#define BUF_BYTES (ROWS * ROWB)       // 67584
#define RED_OFF (2 * BUF_BYTES)       // 135168
#define LDS_TOTAL (RED_OFF + 2048)    // 137216 (red: 2 x 256 f32)

// -------- pack_w: MFMA-fragment-ordered chunks (16x16, as R5/R7) ------------
// Chunk g = (c, kq, n16), 1024 B = 64 lanes x 16 B. Element (lane, j):
//   f = n16*16 + (lane&15), k = kq*32 + (lane>>4)*8 + j, tap = k>>9, d = k&511
//   src = w_c[f][d][tap]  (layout [F][D][Kw]).
__global__ void pack_w_kernel(const float* __restrict__ w3,
                              const float* __restrict__ w4,
                              const float* __restrict__ w5,
                              __bf16* __restrict__ wq) {
    const int t    = blockIdx.x * 256 + threadIdx.x;  // 0..196607
    const int g    = t >> 6;                          // chunk 0..3071
    const int lane = t & 63;
    int rel, Kw; const float* w;
    if (g < 768)       { rel = g;        Kw = 3; w = w3; }
    else if (g < 1792) { rel = g - 768;  Kw = 4; w = w4; }
    else               { rel = g - 1792; Kw = 5; w = w5; }
    const int kq  = rel >> 4;
    const int n16 = rel & 15;
    const int f   = n16 * 16 + (lane & 15);
    const int k0  = kq * 32 + (lane >> 4) * 8;        // frag never straddles tap
    const int tap = k0 >> 9;
    const int d0  = k0 & 511;
    const float* src = w + ((size_t)f * 512 + d0) * Kw + tap;
    bf16x8 o;
#pragma unroll
    for (int j = 0; j < 8; ++j) o[j] = (__bf16)src[j * Kw];
    *(bf16x8*)(wq + (size_t)t * 8) = o;
}

// ---------------- persistent fused gather + conv GEMM -----------------------
__global__ __launch_bounds__(1024, 4) void conv_gemm_kernel(
        const int* __restrict__ text,
        const float* __restrict__ embed,
        const __bf16* __restrict__ wq,
        const float* __restrict__ b3,
        const float* __restrict__ b4,
        const float* __restrict__ b5,
        float* __restrict__ out) {
    extern __shared__ char lds[];
    float* const red = (float*)(lds + RED_OFF);

    const int tid  = threadIdx.x;
    const int lane = tid & 63;
    const int wave = tid >> 6;         // 0..15
    const int wm   = wave & 1;         // m-half 0..1 (64 rows each)
    const int wn   = wave >> 1;        // n-slice 0..7 (32 cols each)
    const int lm = lane & 15, lk = lane >> 4;
    const int sr = tid >> 5;           // staging row-in-pass 0..31
    const int sc = tid & 31;           // staging col 0..31 (x16B)

    // ---- gather staging: 2 passes (64 rows) per pair, 16 B dst/thread ----
    f32x4 G[4];
    auto issuePair = [&](int nbs, int h, int p0) {
#pragma unroll
        for (int p = 0; p < 2; ++p) {
            const int r = (p0 + p) * 32 + sr;
            const int tok = text[nbs * 128 + r];
            const f32x4* src = (const f32x4*)
                (embed + (size_t)tok * 512 + h * 256 + sc * 8);
            G[p * 2]     = __builtin_nontemporal_load(src);
            G[p * 2 + 1] = __builtin_nontemporal_load(src + 1);
        }
    };
    auto writePair = [&](char* bufp, int p0) {
#pragma unroll
        for (int p = 0; p < 2; ++p) {
            const int r = (p0 + p) * 32 + sr;
            const f32x4 v0 = G[p * 2], v1 = G[p * 2 + 1];
            bf16x8 o;
            o[0] = (__bf16)v0.x; o[1] = (__bf16)v0.y;
            o[2] = (__bf16)v0.z; o[3] = (__bf16)v0.w;
            o[4] = (__bf16)v1.x; o[5] = (__bf16)v1.y;
            o[6] = (__bf16)v1.z; o[7] = (__bf16)v1.w;
            *(bf16x8*)(bufp + r * ROWB + ((sc * 16) ^ ((r & 7) << 6))) = o;
        }
    };

    f32x4 acc[4][2];
    bf16x8 B4[4][2];
    const __bf16* bp = wq;             // set per conv

    auto loadB = [&](bf16x8* d, int kb) {
        const __bf16* p = bp + (size_t)kb * 8192;
        d[0] = *(const bf16x8*)(p);
        d[1] = *(const bf16x8*)(p + 512);
    };

    // One d-half phase: KW taps x 8 kq-steps, barrier-free.
    auto runPhase = [&](const char* bufp, int KW, int h) {
        const int kh = h * 8;
        const int maxkq = (KW - 1) * 16 + kh + 7;
        loadB(B4[0], kh);     loadB(B4[1], kh + 1);
        loadB(B4[2], kh + 2); loadB(B4[3], kh + 3);
        for (int tap = 0; tap < KW; ++tap) {
            // swizzled A addr: byte(q) = base[mt] + ((q<<6) ^ e)
            const int e = ((lm + tap) & 7) << 6;
            int base[4];
#pragma unroll
            for (int mt = 0; mt < 4; ++mt)
                base[mt] = (wm * 64 + mt * 16 + lm + tap) * ROWB + lk * 16;
            const int kqt = tap * 16 + kh;
#pragma unroll
            for (int q = 0; q < 8; ++q) {
                bf16x8 a[4];
                const int off = (q << 6) ^ e;
#pragma unroll
                for (int mt = 0; mt < 4; ++mt)
                    a[mt] = *(const bf16x8*)(bufp + base[mt] + off);
                __builtin_amdgcn_s_setprio(1);
#pragma unroll
                for (int nt = 0; nt < 2; ++nt)
#pragma unroll
                    for (int mt = 0; mt < 4; ++mt)
                        acc[mt][nt] = __builtin_amdgcn_mfma_f32_16x16x32_bf16(
                            a[mt], B4[q & 3][nt], acc[mt][nt], 0, 0, 0);
                __builtin_amdgcn_s_setprio(0);
                // B prefetch for step q+4 (ring slot q&3); clamp = dead dup
                int kqn = kqt + ((q < 4) ? (q + 4) : (q + 12));
                kqn = (kqn <= maxkq) ? kqn : maxkq;
                loadB(B4[q & 3], kqn);
            }
        }
    };

    // ---- prolog: stage bs(i=0) both halves + zero pad rows (once) ----
    const int bsbase = blockIdx.x * 4;
    issuePair(bsbase, 0, 0); writePair(lds, 0);
    issuePair(bsbase, 0, 2); writePair(lds, 2);
    issuePair(bsbase, 1, 0); writePair(lds + BUF_BYTES, 0);
    issuePair(bsbase, 1, 2); writePair(lds + BUF_BYTES, 2);
    if (tid < 128) {                   // rows 128..131, both buffers, once
        const int r = 128 + sr;
        const int off = r * ROWB + ((sc * 16) ^ ((r & 7) << 6));
        bf16x8 z = {};
        *(bf16x8*)(lds + off) = z;
        *(bf16x8*)(lds + BUF_BYTES + off) = z;
    }
    __syncthreads();

#pragma unroll 1
    for (int i = 0; i < 4; ++i) {
        const int bs  = bsbase + i;
        const int nbs = bs + 1;
        const bool stg = (i < 3);
#pragma unroll 1
        for (int c = 0; c < 3; ++c) {
            const int KW = 3 + c;
            bp = wq + ((c == 0) ? 0 : (c == 1) ? 393216 : 917504)
                    + (size_t)wn * 1024 + (size_t)lane * 8;
#pragma unroll
            for (int mt = 0; mt < 4; ++mt)
#pragma unroll
                for (int nt = 0; nt < 2; ++nt)
                    acc[mt][nt] = (f32x4){0.f, 0.f, 0.f, 0.f};

            const bool lastc = stg && (c == 2);
            if (lastc) issuePair(nbs, 0, 0);   // h0 rows 0..63: hide under h0
            runPhase(lds, KW, 0);
            if (lastc) {
                __syncthreads();               // all buf0 reads done
                writePair(lds, 0);
                issuePair(nbs, 0, 2);          // short stall (serial)
                writePair(lds, 2);
                issuePair(nbs, 1, 0);          // hide under h1
            }
            runPhase(lds + BUF_BYTES, KW, 1);

            // ---- epilogue conv c: masked max, cross-lane, cross-wave ----
            const int Tv = 126 - c;            // 126/125/124 valid positions
            float cmax[2];
#pragma unroll
            for (int nt = 0; nt < 2; ++nt) {
                float mx = -3.0e38f;
#pragma unroll
                for (int mt = 0; mt < 4; ++mt) {
                    const int mb = wm * 64 + mt * 16 + lk * 4;
#pragma unroll
                    for (int r = 0; r < 4; ++r)
                        if (mb + r < Tv) mx = fmaxf(mx, acc[mt][nt][r]);
                }
                mx = fmaxf(mx, __shfl_xor(mx, 16, 64));
                mx = fmaxf(mx, __shfl_xor(mx, 32, 64));
                cmax[nt] = mx;
            }
            __syncthreads();                   // buf1 reads + prev red done
            if (lastc) {
                writePair(lds + BUF_BYTES, 0);
                issuePair(nbs, 1, 2);          // short stall (serial)
                writePair(lds + BUF_BYTES, 2);
            }
            if (lk == 0) {
#pragma unroll
                for (int nt = 0; nt < 2; ++nt)
                    red[wm * 256 + wn * 32 + nt * 16 + lm] = cmax[nt];
            }
            __syncthreads();
            if (tid < 256) {
                const float* bias = (c == 0) ? b3 : (c == 1) ? b4 : b5;
                const float v = fmaxf(red[tid], red[256 + tid]) + bias[tid];
                out[(size_t)bs * 768 + c * 256 + tid] = fmaxf(v, 0.f);
            }
        }
    }
}

extern "C" void kernel_launch(void* const* d_in, const int* in_sizes, int n_in,
                              void* d_out, int out_size, void* d_ws, size_t ws_size,
                              hipStream_t stream) {
    const int*   text  = (const int*)d_in[0];
    const float* embed = (const float*)d_in[1];
    const float* w3    = (const float*)d_in[2];
    const float* b3    = (const float*)d_in[3];
    const float* w4    = (const float*)d_in[4];
    const float* b4    = (const float*)d_in[5];
    const float* w5    = (const float*)d_in[6];
    const float* b5    = (const float*)d_in[7];
    float* out = (float*)d_out;

    __bf16* wq = (__bf16*)d_ws;                 // 1572864 bf16 = 3.1 MB

    (void)hipFuncSetAttribute((const void*)conv_gemm_kernel,
                              hipFuncAttributeMaxDynamicSharedMemorySize,
                              LDS_TOTAL);

    pack_w_kernel<<<768, 256, 0, stream>>>(w3, w4, w5, wq);
    conv_gemm_kernel<<<256, 1024, LDS_TOTAL, stream>>>(text, embed, wq,
                                                       b3, b4, b5, out);
}